// Round 12
// baseline (536.054 us; speedup 1.0000x reference)
//
#include <hip/hip_runtime.h>
#include <stdint.h>

#define D_DIM 1024

typedef __bf16 bf16x8 __attribute__((ext_vector_type(8)));
typedef float  f32x4  __attribute__((ext_vector_type(4)));

typedef const __attribute__((address_space(1))) void gvoid_t;
typedef __attribute__((address_space(3))) void lvoid_t;

__device__ __forceinline__ void gload_lds16(const void* g, void* l) {
  __builtin_amdgcn_global_load_lds((gvoid_t*)g, (lvoid_t*)l, 16, 0, 0);
}

__device__ __forceinline__ uint16_t f2bf(float f) {
  uint32_t u = __float_as_uint(f);
  u += 0x7fffu + ((u >> 16) & 1u);   // RNE
  return (uint16_t)(u >> 16);
}
__device__ __forceinline__ float bf2f(uint32_t u16) {
  union { uint32_t u; float f; } c; c.u = u16 << 16; return c.f;
}

// ---------------------------------------------------------------- casts ----
// Grid-stride (G11): 2048 blocks, 16 independent iters/thread.
__global__ void __launch_bounds__(256) cast_x_k(const float* __restrict__ x,
                                                uint16_t* __restrict__ xb) {
  const int tid = blockIdx.x * 256 + threadIdx.x;      // 0..524287
#pragma unroll 4
  for (int it = 0; it < 16; ++it) {
    const int64_t c = (int64_t)it * 524288 + tid;      // 8,388,608 chunks
    float4 v = *(const float4*)(x + c * 4);
    ushort4 o;
    o.x = f2bf(v.x); o.y = f2bf(v.y); o.z = f2bf(v.z); o.w = f2bf(v.w);
    *(ushort4*)(xb + c * 4) = o;
  }
}

// 768 blocks, 4 iters/thread over 786432 chunks (3 x 1M elems / 4).
__global__ void __launch_bounds__(256) cast_w_k(const float* __restrict__ Wq,
                                                const float* __restrict__ Wk,
                                                const float* __restrict__ Wv,
                                                uint16_t* __restrict__ wcat) {
  const int tid = blockIdx.x * 256 + threadIdx.x;      // 0..196607
#pragma unroll
  for (int it = 0; it < 4; ++it) {
    const int c = it * 196608 + tid;
    const int wsel = c >> 18;                          // 262144 chunks/matrix
    const int64_t l = (int64_t)(c & 262143) * 4;
    const float* src = (wsel == 0) ? Wq : (wsel == 1) ? Wk : Wv;
    float4 v = *(const float4*)(src + l);
    ushort4 o;
    o.x = f2bf(v.x); o.y = f2bf(v.y); o.z = f2bf(v.z); o.w = f2bf(v.w);
    *(ushort4*)(wcat + (int64_t)c * 4) = o;
  }
}

// ----------------------------------------------------------------- GEMM ----
// (byte-identical anchor from round 9: 256x256, 8-phase, counted vmcnt,
//  3-bit slot swizzle — SQ_LDS_BANK_CONFLICT == 0 verified)
__global__ void __launch_bounds__(512, 2) gemm_qkv8(
    const uint16_t* __restrict__ xb, const uint16_t* __restrict__ wcat,
    float* __restrict__ outQ, uint16_t* __restrict__ Kb,
    uint16_t* __restrict__ Vb) {
  alignas(16) __shared__ uint16_t sA[2][16384];
  alignas(16) __shared__ uint16_t sB[2][16384];
  const int tid = threadIdx.x, lane = tid & 63, wid = tid >> 6;
  const int wm = wid >> 2, wn = wid & 3;

  const int bid = blockIdx.x;
  const int wg = (bid & 7) * 192 + (bid >> 3);
  const int tm = wg / 12, tn = wg % 12;
  const int row0 = tm * 256, e0 = tn * 256;

  const int c0 = tid;
  const int c1 = tid + 512;
  const int cs0 = c0 ^ ((c0 >> 3) & 7);
  const int cs1 = c1 ^ ((c1 >> 3) & 7);
  const int sr0 = cs0 >> 3, sk0 = (cs0 & 7) * 8;
  const int sr1 = cs1 >> 3, sk1 = (cs1 & 7) * 8;
  const uint16_t* gA = xb + (int64_t)row0 * D_DIM;
  const uint16_t* gB = wcat + (int64_t)e0 * D_DIM;
  const int ldsw = wid * 512;

  const int lr = lane & 15, kg = lane >> 4;
  const int kq0 = (kg ^ (lr & 7)) * 8;
  const int kq1 = kq0 ^ 32;
  const int arow = (wm * 128 + lr) * 64;
  const int brow = (wn * 64 + lr) * 64;

  f32x4 acc[8][4] = {};
  bf16x8 bfr[4][2];

#define STAGE_A(d, h, kt) do {                                               \
    gload_lds16(gA + (int64_t)((h)*128 + sr0) * D_DIM + (kt) + sk0,          \
                &sA[d][(h)*8192 + ldsw]);                                    \
    gload_lds16(gA + (int64_t)((h)*128 + sr1) * D_DIM + (kt) + sk1,          \
                &sA[d][(h)*8192 + 4096 + ldsw]);                             \
  } while (0)
#define STAGE_B(d, h, kt) do {                                               \
    gload_lds16(gB + (int64_t)((h)*128 + sr0) * D_DIM + (kt) + sk0,          \
                &sB[d][(h)*8192 + ldsw]);                                    \
    gload_lds16(gB + (int64_t)((h)*128 + sr1) * D_DIM + (kt) + sk1,          \
                &sB[d][(h)*8192 + 4096 + ldsw]);                             \
  } while (0)

#define MFMA __builtin_amdgcn_mfma_f32_16x16x32_bf16
#define PHASE(qq, dd, STAGE_STMT, VM_STMT) do {                              \
    if ((qq) == 0) {                                                         \
      bfr[0][0] = *(const bf16x8*)&sB[dd][brow + 0 * 1024 + kq0];            \
      bfr[0][1] = *(const bf16x8*)&sB[dd][brow + 0 * 1024 + kq1];            \
      bfr[1][0] = *(const bf16x8*)&sB[dd][brow + 1 * 1024 + kq0];            \
      bfr[1][1] = *(const bf16x8*)&sB[dd][brow + 1 * 1024 + kq1];            \
      bfr[2][0] = *(const bf16x8*)&sB[dd][brow + 2 * 1024 + kq0];            \
      bfr[2][1] = *(const bf16x8*)&sB[dd][brow + 2 * 1024 + kq1];            \
      bfr[3][0] = *(const bf16x8*)&sB[dd][brow + 3 * 1024 + kq0];            \
      bfr[3][1] = *(const bf16x8*)&sB[dd][brow + 3 * 1024 + kq1];            \
    }                                                                        \
    bf16x8 a00 = *(const bf16x8*)&sA[dd][arow + (2*(qq)) * 1024 + kq0];      \
    bf16x8 a01 = *(const bf16x8*)&sA[dd][arow + (2*(qq)) * 1024 + kq1];      \
    bf16x8 a10 = *(const bf16x8*)&sA[dd][arow + (2*(qq)+1) * 1024 + kq0];    \
    bf16x8 a11 = *(const bf16x8*)&sA[dd][arow + (2*(qq)+1) * 1024 + kq1];    \
    STAGE_STMT;                                                              \
    asm volatile("" ::: "memory");                                           \
    __builtin_amdgcn_s_barrier();                                            \
    __builtin_amdgcn_s_setprio(1);                                           \
    acc[2*(qq)][0]   = MFMA(a00, bfr[0][0], acc[2*(qq)][0],   0,0,0);        \
    acc[2*(qq)+1][0] = MFMA(a10, bfr[0][0], acc[2*(qq)+1][0], 0,0,0);        \
    acc[2*(qq)][0]   = MFMA(a01, bfr[0][1], acc[2*(qq)][0],   0,0,0);        \
    acc[2*(qq)+1][0] = MFMA(a11, bfr[0][1], acc[2*(qq)+1][0], 0,0,0);        \
    acc[2*(qq)][1]   = MFMA(a00, bfr[1][0], acc[2*(qq)][1],   0,0,0);        \
    acc[2*(qq)+1][1] = MFMA(a10, bfr[1][0], acc[2*(qq)+1][1], 0,0,0);        \
    acc[2*(qq)][1]   = MFMA(a01, bfr[1][1], acc[2*(qq)][1],   0,0,0);        \
    acc[2*(qq)+1][1] = MFMA(a11, bfr[1][1], acc[2*(qq)+1][1], 0,0,0);        \
    acc[2*(qq)][2]   = MFMA(a00, bfr[2][0], acc[2*(qq)][2],   0,0,0);        \
    acc[2*(qq)+1][2] = MFMA(a10, bfr[2][0], acc[2*(qq)+1][2], 0,0,0);        \
    acc[2*(qq)][2]   = MFMA(a01, bfr[2][1], acc[2*(qq)][2],   0,0,0);        \
    acc[2*(qq)+1][2] = MFMA(a11, bfr[2][1], acc[2*(qq)+1][2], 0,0,0);        \
    acc[2*(qq)][3]   = MFMA(a00, bfr[3][0], acc[2*(qq)][3],   0,0,0);        \
    acc[2*(qq)+1][3] = MFMA(a10, bfr[3][0], acc[2*(qq)+1][3], 0,0,0);        \
    acc[2*(qq)][3]   = MFMA(a01, bfr[3][1], acc[2*(qq)][3],   0,0,0);        \
    acc[2*(qq)+1][3] = MFMA(a11, bfr[3][1], acc[2*(qq)+1][3], 0,0,0);        \
    __builtin_amdgcn_s_setprio(0);                                           \
    VM_STMT;                                                                 \
    asm volatile("" ::: "memory");                                           \
    __builtin_amdgcn_s_barrier();                                            \
  } while (0)

  STAGE_B(0, 0, 0);  STAGE_B(0, 1, 0);
  STAGE_A(0, 0, 0);  STAGE_A(0, 1, 0);
  STAGE_B(1, 0, 64); STAGE_B(1, 1, 64);
  asm volatile("s_waitcnt vmcnt(4)" ::: "memory");
  __builtin_amdgcn_s_barrier();

  int ktb = 0;
  for (int i = 0; i < 8; ++i) {
    const bool nl = (i < 7);
    const int kt1 = ktb + 64, kt2 = ktb + 128, kt3 = ktb + 192;
    PHASE(0, 0, STAGE_A(1, 0, kt1), ((void)0));
    PHASE(1, 0, STAGE_A(1, 1, kt1), ((void)0));
    PHASE(2, 0, if (nl) STAGE_B(0, 0, kt2), ((void)0));
    PHASE(3, 0, if (nl) STAGE_B(0, 1, kt2),
          { if (nl) asm volatile("s_waitcnt vmcnt(4)" ::: "memory");
            else    asm volatile("s_waitcnt vmcnt(0)" ::: "memory"); });
    PHASE(0, 1, if (nl) STAGE_A(0, 0, kt2), ((void)0));
    PHASE(1, 1, if (nl) STAGE_A(0, 1, kt2), ((void)0));
    PHASE(2, 1, if (nl) STAGE_B(1, 0, kt3), ((void)0));
    PHASE(3, 1, if (nl) STAGE_B(1, 1, kt3),
          { if (nl) asm volatile("s_waitcnt vmcnt(4)" ::: "memory"); });
    ktb += 128;
  }

  const int proj = e0 >> 10;  // 0=Q,1=K,2=V
  if (proj == 0) {
    float* o = outQ + (int64_t)(row0 + wm * 128) * D_DIM + e0 + wn * 64;
#pragma unroll
    for (int m = 0; m < 8; ++m)
#pragma unroll
      for (int rr = 0; rr < 4; ++rr) {
        const int64_t rofs = (int64_t)(m * 16 + kg * 4 + rr) * D_DIM;
#pragma unroll
        for (int n = 0; n < 4; ++n)
          o[rofs + n * 16 + lr] = acc[m][n][rr];
      }
  } else {
    uint16_t* o = (proj == 1 ? Kb : Vb) +
                  (int64_t)(row0 + wm * 128) * D_DIM + (e0 - proj * 1024) + wn * 64;
#pragma unroll
    for (int m = 0; m < 8; ++m)
#pragma unroll
      for (int rr = 0; rr < 4; ++rr) {
        const int64_t rofs = (int64_t)(m * 16 + kg * 4 + rr) * D_DIM;
#pragma unroll
        for (int n = 0; n < 4; ++n)
          o[rofs + n * 16 + lr] = f2bf(acc[m][n][rr]);
      }
  }
#undef PHASE
#undef MFMA
#undef STAGE_A
#undef STAGE_B
}

// ---------------------------------------------- gf = sum_n K_hat .* V -----
// (unchanged anchor) 1024 blocks; wave-per-row shuffle-only reduction.
__global__ void __launch_bounds__(256) kv_partial(
    const uint16_t* __restrict__ Kb, const uint16_t* __restrict__ Vb,
    float* __restrict__ partial) {
  const int blk = blockIdx.x;              // 0..1023
  const int b = blk >> 7, g = blk & 127;   // 32 rows per block
  const int t = threadIdx.x;
  const int w = t >> 6, lane = t & 63;
  __shared__ float sacc[4][1024];
  float acc[16];
#pragma unroll
  for (int j = 0; j < 16; ++j) acc[j] = 0.f;
  const int64_t rbase = ((int64_t)b * 4096 + g * 32 + w * 8) * D_DIM;
#pragma unroll 2
  for (int r = 0; r < 8; ++r) {
    const int64_t row = rbase + (int64_t)r * D_DIM;
    float k[16], v[16];
#pragma unroll
    for (int p = 0; p < 2; ++p) {
      const int off = (p * 64 + lane) * 8;
      const uint4 ku = *(const uint4*)(Kb + row + off);
      const uint4 vu = *(const uint4*)(Vb + row + off);
      const uint32_t kw[4] = {ku.x, ku.y, ku.z, ku.w};
      const uint32_t vw[4] = {vu.x, vu.y, vu.z, vu.w};
#pragma unroll
      for (int q = 0; q < 4; ++q) {
        k[p * 8 + q * 2]     = bf2f(kw[q] & 0xffffu);
        k[p * 8 + q * 2 + 1] = bf2f(kw[q] >> 16);
        v[p * 8 + q * 2]     = bf2f(vw[q] & 0xffffu);
        v[p * 8 + q * 2 + 1] = bf2f(vw[q] >> 16);
      }
    }
    float ss = 0.f;
#pragma unroll
    for (int j = 0; j < 16; ++j) ss += k[j] * k[j];
#pragma unroll
    for (int o = 32; o > 0; o >>= 1) ss += __shfl_xor(ss, o);
    const float rn = 1.0f / fmaxf(sqrtf(ss), 1e-12f);
#pragma unroll
    for (int j = 0; j < 16; ++j) acc[j] += k[j] * v[j] * rn;
  }
#pragma unroll
  for (int p = 0; p < 2; ++p)
#pragma unroll
    for (int j = 0; j < 8; ++j)
      sacc[w][p * 512 + lane * 8 + j] = acc[p * 8 + j];
  __syncthreads();
  float* prow = partial + (int64_t)blk * 1024;
#pragma unroll
  for (int c = t; c < 1024; c += 256)
    prow[c] = sacc[0][c] + sacc[1][c] + sacc[2][c] + sacc[3][c];
}

// 4 independent accumulators -> MLP-friendly; 32 blocks.
__global__ void __launch_bounds__(256) kv_reduce(const float* __restrict__ partial,
                                                 float* __restrict__ gf) {
  const int i = blockIdx.x * 256 + threadIdx.x;  // 0..8191
  const int b = i >> 10, e = i & 1023;
  const float* p = partial + ((int64_t)b * 128 << 10) + e;
  float s0 = 0.f, s1 = 0.f, s2 = 0.f, s3 = 0.f;
#pragma unroll 8
  for (int g = 0; g < 128; g += 4) {
    s0 += p[(int64_t)(g + 0) << 10];
    s1 += p[(int64_t)(g + 1) << 10];
    s2 += p[(int64_t)(g + 2) << 10];
    s3 += p[(int64_t)(g + 3) << 10];
  }
  gf[i] = (s0 + s1) + (s2 + s3);
}

// -------------------------------- out = (Q/||Q||) * gf[b]   (in place) ----
// 2048 blocks x 4 waves x 4 rows: preload all 4 rows, interleave the 4
// shuffle-reduction chains, then scale+store (ILP over the serial chain).
__global__ void __launch_bounds__(256) finalize_out(float* __restrict__ out,
                                                    const float* __restrict__ gf) {
  const int w = threadIdx.x >> 6, lane = threadIdx.x & 63;
  const int64_t base = (int64_t)blockIdx.x * 16 + w * 4;  // 16 | 4096 -> same b
  const int b = (int)(base >> 12);
  const float* gp = gf + (int64_t)b * D_DIM;
  float4 g4[4], q[4][4];
#pragma unroll
  for (int p = 0; p < 4; ++p) g4[p] = *(const float4*)(gp + (p * 64 + lane) * 4);
#pragma unroll
  for (int r = 0; r < 4; ++r)
#pragma unroll
    for (int p = 0; p < 4; ++p)
      q[r][p] = *(const float4*)(out + (base + r) * D_DIM + (p * 64 + lane) * 4);
  float ss[4];
#pragma unroll
  for (int r = 0; r < 4; ++r) {
    ss[r] = 0.f;
#pragma unroll
    for (int p = 0; p < 4; ++p)
      ss[r] += q[r][p].x * q[r][p].x + q[r][p].y * q[r][p].y +
               q[r][p].z * q[r][p].z + q[r][p].w * q[r][p].w;
  }
#pragma unroll
  for (int o = 32; o > 0; o >>= 1) {
#pragma unroll
    for (int r = 0; r < 4; ++r) ss[r] += __shfl_xor(ss[r], o);
  }
#pragma unroll
  for (int r = 0; r < 4; ++r) {
    const float rn = 1.0f / fmaxf(sqrtf(ss[r]), 1e-12f);
#pragma unroll
    for (int p = 0; p < 4; ++p) {
      float4 v = q[r][p];
      v.x *= rn * g4[p].x; v.y *= rn * g4[p].y;
      v.z *= rn * g4[p].z; v.w *= rn * g4[p].w;
      *(float4*)(out + (base + r) * D_DIM + (p * 64 + lane) * 4) = v;
    }
  }
}

// -------------------------------------------------------------- launch ----
extern "C" void kernel_launch(void* const* d_in, const int* in_sizes, int n_in,
                              void* d_out, int out_size, void* d_ws, size_t ws_size,
                              hipStream_t stream) {
  const float* x  = (const float*)d_in[0];
  const float* Wq = (const float*)d_in[1];
  const float* Wk = (const float*)d_in[2];
  const float* Wv = (const float*)d_in[3];
  float* out = (float*)d_out;

  uint8_t* w = (uint8_t*)d_ws;
  uint16_t* xb   = (uint16_t*)(w);
  uint16_t* wcat = (uint16_t*)(w + (size_t)67108864);
  uint16_t* Kb   = (uint16_t*)(w + (size_t)73400320);
  uint16_t* Vb   = (uint16_t*)(w + (size_t)140509184);
  float* partial = (float*)(w);                         // aliases xb (dead)
  float* gf      = (float*)(w + (size_t)4194304);

  cast_x_k   <<<2048, 256, 0, stream>>>(x, xb);
  cast_w_k   <<<768, 256, 0, stream>>>(Wq, Wk, Wv, wcat);
  gemm_qkv8  <<<1536, 512, 0, stream>>>(xb, wcat, out, Kb, Vb);
  kv_partial <<<1024, 256, 0, stream>>>(Kb, Vb, partial);
  kv_reduce  <<<32, 256, 0, stream>>>(partial, gf);
  finalize_out<<<2048, 256, 0, stream>>>(out, gf);
}